// Round 5
// baseline (2278.485 us; speedup 1.0000x reference)
//
#include <hip/hip_runtime.h>

// CapsAll on MI355X — round 5: barrier-free direct-global MFMA K-loops
// (AITER-style buffer_load<->MFMA interleave), r-in-grid chunking for L2
// x-reuse, __expf softmax.
//
//   k0h: fp32 -> bf16(hi) plane  (W1, W2, x)
//   k0t: cw [r][k][n] fp32 -> cwh/cwl [r][n][k] bf16 (transpose+split)
//   k1:  hbar = relu(x @ WS1_r^T), A/B frags loaded direct from global,
//        no LDS, no barriers. r = blockIdx.z.  (fallback: LDS-staged, fp32 x)
//   k2:  scores = Hh @ WS2_r^T (256x64 reg tile) direct-global frags +
//        fused col-softmax (__expf) + m.  r = blockIdx.z.
//   k3:  votes = m @ cw, 2-pass MFMA (fallback fp32 VALU)
//   k4:  dynamic routing
//
// ws (MB): m 4@0 | votes 8@4 | W1h 8@12 | W2h 8@20 | [CWh 32@28 CWl 32@60]
//          | [Xbf 64@92] | Hh @{156|92|28}: 8r x CB x 256 x 512 bf16

typedef __attribute__((ext_vector_type(8))) short bf16x8;
typedef __attribute__((ext_vector_type(8))) unsigned short u16x8;
typedef __attribute__((ext_vector_type(4))) float f32x4;

#define LDT 40  // LDS row stride (bf16 units) for the fallback k1

__device__ __forceinline__ unsigned short f2bf(float f) {
    unsigned u = __float_as_uint(f);
    u += 0x7FFF + ((u >> 16) & 1);           // RNE
    return (unsigned short)(u >> 16);
}
__device__ __forceinline__ float bf2f(unsigned short h) {
    return __uint_as_float(((unsigned)h) << 16);
}

// ---------------- k0h: fp32 -> bf16 hi plane ----------------
__global__ __launch_bounds__(256) void k0_hi(const float* __restrict__ src,
                                             unsigned short* __restrict__ hi,
                                             int n4) {
    int i = blockIdx.x * 256 + threadIdx.x;
    if (i >= n4) return;
    float4 v = ((const float4*)src)[i];
    ushort4 h;
    h.x = f2bf(v.x); h.y = f2bf(v.y); h.z = f2bf(v.z); h.w = f2bf(v.w);
    ((ushort4*)hi)[i] = h;
}

// ------- k0t: cw [r][k=1024][n=2048] fp32 -> [r][n][k] bf16 hi+lo -------
__global__ __launch_bounds__(256) void k0_tsplit(const float* __restrict__ cw,
                                                 unsigned short* __restrict__ ch,
                                                 unsigned short* __restrict__ cl) {
    __shared__ unsigned short Th[64 * 68], Tl[64 * 68];
    const int tid = threadIdx.x;
    const int n0 = blockIdx.x * 64, k0 = blockIdx.y * 64, r = blockIdx.z;
    const float* src = cw + (size_t)r * 1024 * 2048;
#pragma unroll
    for (int p = 0; p < 4; p++) {
        const int kl = p * 16 + (tid >> 4);
        const int nl = (tid & 15) * 4;
        float4 v = *(const float4*)(src + (size_t)(k0 + kl) * 2048 + n0 + nl);
        float vv[4] = {v.x, v.y, v.z, v.w};
#pragma unroll
        for (int e = 0; e < 4; e++) {
            unsigned short h = f2bf(vv[e]);
            Th[(nl + e) * 68 + kl] = h;
            Tl[(nl + e) * 68 + kl] = f2bf(vv[e] - bf2f(h));
        }
    }
    __syncthreads();
    const int nl = tid >> 2, kl = (tid & 3) * 16;
    unsigned short* dh = ch + ((size_t)r * 2048 + n0 + nl) * 1024 + k0 + kl;
    unsigned short* dl = cl + ((size_t)r * 2048 + n0 + nl) * 1024 + k0 + kl;
    *(u16x8*)(dh)     = *(const u16x8*)&Th[nl * 68 + kl];
    *(u16x8*)(dh + 8) = *(const u16x8*)&Th[nl * 68 + kl + 8];
    *(u16x8*)(dl)     = *(const u16x8*)&Tl[nl * 68 + kl];
    *(u16x8*)(dl + 8) = *(const u16x8*)&Tl[nl * 68 + kl + 8];
}

// -------- k1 direct: hbar = relu(Xbf @ W1^T), no LDS, no barriers --------
// Xc = Xbf chunk base [cb*256 x 1024] bf16. grid (cb*2 m-tiles, 4 n, 8 r).
__global__ __launch_bounds__(256) void k1_direct(
    const unsigned short* __restrict__ Xc,
    const unsigned short* __restrict__ W1h,
    unsigned short* __restrict__ Hh, int cb) {
    const int tid = threadIdx.x;
    const int m0 = blockIdx.x * 128, n0 = blockIdx.y * 128, r = blockIdx.z;
    const int wave = tid >> 6, lane = tid & 63;
    const int wm = (wave >> 1) * 64, wn = (wave & 1) * 64;
    const int lx = lane & 15, qd = lane >> 4;

    const unsigned short* pa[4];
    const unsigned short* pb[4];
#pragma unroll
    for (int i = 0; i < 4; i++)
        pa[i] = Xc + (size_t)(m0 + wm + 16 * i + lx) * 1024 + 8 * qd;
#pragma unroll
    for (int j = 0; j < 4; j++)
        pb[j] = W1h + ((size_t)r * 512 + n0 + wn + 16 * j + lx) * 1024 + 8 * qd;

    f32x4 acc[4][4];
#pragma unroll
    for (int i = 0; i < 4; i++)
#pragma unroll
        for (int j = 0; j < 4; j++) acc[i][j] = (f32x4){0.f, 0.f, 0.f, 0.f};

    bf16x8 fa[2][4], fb[2][4];
#pragma unroll
    for (int i = 0; i < 4; i++) fa[0][i] = *(const bf16x8*)(pa[i]);
#pragma unroll
    for (int j = 0; j < 4; j++) fb[0][j] = *(const bf16x8*)(pb[j]);

#pragma unroll
    for (int kk = 0; kk < 32; kk++) {
        const int cur = kk & 1, nxt = cur ^ 1;
        if (kk < 31) {
#pragma unroll
            for (int i = 0; i < 4; i++) fa[nxt][i] = *(const bf16x8*)(pa[i] + (kk + 1) * 32);
#pragma unroll
            for (int j = 0; j < 4; j++) fb[nxt][j] = *(const bf16x8*)(pb[j] + (kk + 1) * 32);
        }
#pragma unroll
        for (int i = 0; i < 4; i++)
#pragma unroll
            for (int j = 0; j < 4; j++)
                acc[i][j] = __builtin_amdgcn_mfma_f32_16x16x32_bf16(fa[cur][i], fb[cur][j], acc[i][j], 0, 0, 0);
    }

    unsigned short* out = Hh + (size_t)r * cb * 256 * 512;
#pragma unroll
    for (int i = 0; i < 4; i++)
#pragma unroll
        for (int j = 0; j < 4; j++) {
            const int col = n0 + wn + 16 * j + lx;
#pragma unroll
            for (int p = 0; p < 4; p++) {
                const int row = m0 + wm + 16 * i + 4 * qd + p;
                out[(size_t)row * 512 + col] = f2bf(fmaxf(acc[i][j][p], 0.f));
            }
        }
}

// -------- k1 fallback: LDS-staged, fp32 x inline-converted (small ws) --------
__global__ __launch_bounds__(256) void k1_lds(
    const float* __restrict__ Xc,
    const unsigned short* __restrict__ W1h,
    unsigned short* __restrict__ Hh, int cb) {
    __shared__ unsigned short Ah[128 * LDT];
    __shared__ unsigned short Bh[128 * LDT];
    const int tid = threadIdx.x;
    const int m0 = blockIdx.x * 128, n0 = blockIdx.y * 128, r = blockIdx.z;
    const int wave = tid >> 6, lane = tid & 63;
    const int wm = (wave >> 1) * 64, wn = (wave & 1) * 64;
    const int lx = lane & 15, qd = lane >> 4;
    const int srow = tid >> 1, scol = (tid & 1) * 16;

    f32x4 acc[4][4];
#pragma unroll
    for (int i = 0; i < 4; i++)
#pragma unroll
        for (int j = 0; j < 4; j++) acc[i][j] = (f32x4){0.f, 0.f, 0.f, 0.f};

    const float* xrow = Xc + (size_t)(m0 + srow) * 1024 + scol;
    const unsigned short* whrow = W1h + ((size_t)r * 512 + n0 + srow) * 1024 + scol;
    unsigned short* ah = &Ah[srow * LDT + scol];
    unsigned short* bh = &Bh[srow * LDT + scol];

    for (int k0 = 0; k0 < 1024; k0 += 32) {
        float4 v0 = *(const float4*)(xrow + k0);
        float4 v1 = *(const float4*)(xrow + k0 + 4);
        float4 v2 = *(const float4*)(xrow + k0 + 8);
        float4 v3 = *(const float4*)(xrow + k0 + 12);
        float vv[16] = {v0.x, v0.y, v0.z, v0.w, v1.x, v1.y, v1.z, v1.w,
                        v2.x, v2.y, v2.z, v2.w, v3.x, v3.y, v3.z, v3.w};
        u16x8 p0, p1;
#pragma unroll
        for (int e = 0; e < 8; e++) p0[e] = f2bf(vv[e]);
#pragma unroll
        for (int e = 0; e < 8; e++) p1[e] = f2bf(vv[8 + e]);
        *(u16x8*)(ah) = p0; *(u16x8*)(ah + 8) = p1;
        u16x8 b0 = *(const u16x8*)(whrow + k0);
        u16x8 b1 = *(const u16x8*)(whrow + k0 + 8);
        *(u16x8*)(bh) = b0; *(u16x8*)(bh + 8) = b1;
        __syncthreads();

        bf16x8 fa[4], fb[4];
#pragma unroll
        for (int i = 0; i < 4; i++) {
            fa[i] = *(const bf16x8*)&Ah[(wm + 16 * i + lx) * LDT + 8 * qd];
            fb[i] = *(const bf16x8*)&Bh[(wn + 16 * i + lx) * LDT + 8 * qd];
        }
#pragma unroll
        for (int i = 0; i < 4; i++)
#pragma unroll
            for (int j = 0; j < 4; j++)
                acc[i][j] = __builtin_amdgcn_mfma_f32_16x16x32_bf16(fa[i], fb[j], acc[i][j], 0, 0, 0);
        __syncthreads();
    }

    unsigned short* out = Hh + (size_t)r * cb * 256 * 512;
#pragma unroll
    for (int i = 0; i < 4; i++)
#pragma unroll
        for (int j = 0; j < 4; j++) {
            const int col = n0 + wn + 16 * j + lx;
#pragma unroll
            for (int p = 0; p < 4; p++) {
                const int row = m0 + wm + 16 * i + 4 * qd + p;
                out[(size_t)row * 512 + col] = f2bf(fmaxf(acc[i][j][p], 0.f));
            }
        }
}

// ------- k2: scores (256x64 reg tile) direct-global + softmax + m -------
// grid (cb b-blocks, 16 u, 8 r). No LDS/barriers in the K-loop.
__global__ __launch_bounds__(256) void k2_mfma(
    const unsigned short* __restrict__ Hh,
    const unsigned short* __restrict__ W2h,
    const float* __restrict__ x, float* __restrict__ m_out, int b0, int cb) {
    __shared__ float mred[4 * 64], sred[4 * 64], pred[4 * 64];
    const int tid = threadIdx.x;
    const int b_local = blockIdx.x, b = b0 + b_local;
    const int u0 = blockIdx.y * 64, r = blockIdx.z;
    const int wave = tid >> 6, lane = tid & 63;
    const int lx = lane & 15, qd = lane >> 4;

    const unsigned short* a0 =
        Hh + ((size_t)(r * cb + b_local)) * 256 * 512;
    const unsigned short* pa[4];
    const unsigned short* pb[4];
#pragma unroll
    for (int i = 0; i < 4; i++)
        pa[i] = a0 + (size_t)(64 * wave + 16 * i + lx) * 512 + 8 * qd;
#pragma unroll
    for (int j = 0; j < 4; j++)
        pb[j] = W2h + ((size_t)r * 1024 + u0 + 16 * j + lx) * 512 + 8 * qd;

    f32x4 acc[4][4];
#pragma unroll
    for (int i = 0; i < 4; i++)
#pragma unroll
        for (int j = 0; j < 4; j++) acc[i][j] = (f32x4){0.f, 0.f, 0.f, 0.f};

    bf16x8 fa[2][4], fb[2][4];
#pragma unroll
    for (int i = 0; i < 4; i++) fa[0][i] = *(const bf16x8*)(pa[i]);
#pragma unroll
    for (int j = 0; j < 4; j++) fb[0][j] = *(const bf16x8*)(pb[j]);

#pragma unroll
    for (int kk = 0; kk < 16; kk++) {
        const int cur = kk & 1, nxt = cur ^ 1;
        if (kk < 15) {
#pragma unroll
            for (int i = 0; i < 4; i++) fa[nxt][i] = *(const bf16x8*)(pa[i] + (kk + 1) * 32);
#pragma unroll
            for (int j = 0; j < 4; j++) fb[nxt][j] = *(const bf16x8*)(pb[j] + (kk + 1) * 32);
        }
#pragma unroll
        for (int i = 0; i < 4; i++)
#pragma unroll
            for (int j = 0; j < 4; j++)
                acc[i][j] = __builtin_amdgcn_mfma_f32_16x16x32_bf16(fa[cur][i], fb[cur][j], acc[i][j], 0, 0, 0);
    }

    // ---- column max over t ----
    float cm[4];
#pragma unroll
    for (int j = 0; j < 4; j++) {
        float mx = acc[0][j][0];
#pragma unroll
        for (int i = 0; i < 4; i++)
#pragma unroll
            for (int p = 0; p < 4; p++) mx = fmaxf(mx, acc[i][j][p]);
        mx = fmaxf(mx, __shfl_xor(mx, 16, 64));
        mx = fmaxf(mx, __shfl_xor(mx, 32, 64));
        if (qd == 0) mred[wave * 64 + 16 * j + lx] = mx;
    }
    __syncthreads();
#pragma unroll
    for (int j = 0; j < 4; j++) {
        const int c = 16 * j + lx;
        cm[j] = fmaxf(fmaxf(mred[c], mred[64 + c]), fmaxf(mred[128 + c], mred[192 + c]));
    }

    // ---- exp + weighted sum against x ----
    float ds[4] = {0.f, 0.f, 0.f, 0.f}, pm[4] = {0.f, 0.f, 0.f, 0.f};
    const float* xb = x + (size_t)b * 256 * 1024 + u0;
#pragma unroll
    for (int i = 0; i < 4; i++) {
#pragma unroll
        for (int p = 0; p < 4; p++) {
            const int t = 64 * wave + 16 * i + 4 * qd + p;
            const float* xr = xb + (size_t)t * 1024;
            float xv[4];
#pragma unroll
            for (int j = 0; j < 4; j++) xv[j] = xr[16 * j + lx];
#pragma unroll
            for (int j = 0; j < 4; j++) {
                float e = __expf(acc[i][j][p] - cm[j]);
                ds[j] += e;
                pm[j] += e * xv[j];
            }
        }
    }
#pragma unroll
    for (int j = 0; j < 4; j++) {
        ds[j] += __shfl_xor(ds[j], 16, 64);
        ds[j] += __shfl_xor(ds[j], 32, 64);
        pm[j] += __shfl_xor(pm[j], 16, 64);
        pm[j] += __shfl_xor(pm[j], 32, 64);
        if (qd == 0) {
            sred[wave * 64 + 16 * j + lx] = ds[j];
            pred[wave * 64 + 16 * j + lx] = pm[j];
        }
    }
    __syncthreads();
    if (tid < 64) {
        float dsum = sred[tid] + sred[64 + tid] + sred[128 + tid] + sred[192 + tid];
        float psum = pred[tid] + pred[64 + tid] + pred[128 + tid] + pred[192 + tid];
        m_out[(size_t)(r * 128 + b) * 1024 + u0 + tid] = psum / dsum;
    }
}

// ------- k3 (MFMA): votes = m @ cw, cw split [r][n][k] hi/lo, 2-pass -------
__global__ __launch_bounds__(256) void k3_votes_mfma(
    const float* __restrict__ Mb,
    const unsigned short* __restrict__ CWh,
    const unsigned short* __restrict__ CWl,
    float* __restrict__ V) {
    __shared__ unsigned short Ah[128 * LDT];
    __shared__ unsigned short Bh[64 * LDT], Bl[64 * LDT];
    const int tid = threadIdx.x;
    const int r = blockIdx.x, n0 = blockIdx.y * 64;
    const int wave = tid >> 6, lane = tid & 63;
    const int wr = wave >> 1, wc = wave & 1;
    const int lx = lane & 15, qd = lane >> 4;
    const int srow = tid >> 1, scol = (tid & 1) * 16;
    const int brow = tid >> 2, bcol = (tid & 3) * 8;

    const float* arow = Mb + (size_t)(r * 128 + srow) * 1024 + scol;
    const unsigned short* bhrow = CWh + ((size_t)r * 2048 + n0 + brow) * 1024 + bcol;
    const unsigned short* blrow = CWl + ((size_t)r * 2048 + n0 + brow) * 1024 + bcol;

    f32x4 acc[4][2];
#pragma unroll
    for (int i = 0; i < 4; i++)
#pragma unroll
        for (int j = 0; j < 2; j++) acc[i][j] = (f32x4){0.f, 0.f, 0.f, 0.f};

    for (int k0 = 0; k0 < 1024; k0 += 32) {
        float4 v0 = *(const float4*)(arow + k0);
        float4 v1 = *(const float4*)(arow + k0 + 4);
        float4 v2 = *(const float4*)(arow + k0 + 8);
        float4 v3 = *(const float4*)(arow + k0 + 12);
        float vv[16] = {v0.x, v0.y, v0.z, v0.w, v1.x, v1.y, v1.z, v1.w,
                        v2.x, v2.y, v2.z, v2.w, v3.x, v3.y, v3.z, v3.w};
        u16x8 p0, p1;
#pragma unroll
        for (int e = 0; e < 8; e++) p0[e] = f2bf(vv[e]);
#pragma unroll
        for (int e = 0; e < 8; e++) p1[e] = f2bf(vv[8 + e]);
        *(u16x8*)&Ah[srow * LDT + scol] = p0;
        *(u16x8*)&Ah[srow * LDT + scol + 8] = p1;
        *(u16x8*)&Bh[brow * LDT + bcol] = *(const u16x8*)(bhrow + k0);
        *(u16x8*)&Bl[brow * LDT + bcol] = *(const u16x8*)(blrow + k0);
        __syncthreads();

        bf16x8 fa[4], fbh[2], fbl[2];
#pragma unroll
        for (int i = 0; i < 4; i++)
            fa[i] = *(const bf16x8*)&Ah[(64 * wr + 16 * i + lx) * LDT + 8 * qd];
#pragma unroll
        for (int j = 0; j < 2; j++) {
            fbh[j] = *(const bf16x8*)&Bh[(32 * wc + 16 * j + lx) * LDT + 8 * qd];
            fbl[j] = *(const bf16x8*)&Bl[(32 * wc + 16 * j + lx) * LDT + 8 * qd];
        }
#pragma unroll
        for (int i = 0; i < 4; i++)
#pragma unroll
            for (int j = 0; j < 2; j++)
                acc[i][j] = __builtin_amdgcn_mfma_f32_16x16x32_bf16(fa[i], fbh[j], acc[i][j], 0, 0, 0);
#pragma unroll
        for (int i = 0; i < 4; i++)
#pragma unroll
            for (int j = 0; j < 2; j++)
                acc[i][j] = __builtin_amdgcn_mfma_f32_16x16x32_bf16(fa[i], fbl[j], acc[i][j], 0, 0, 0);
        __syncthreads();
    }

#pragma unroll
    for (int i = 0; i < 4; i++)
#pragma unroll
        for (int j = 0; j < 2; j++) {
            const int col = n0 + 32 * wc + 16 * j + lx;
#pragma unroll
            for (int p = 0; p < 4; p++) {
                const int row = 64 * wr + 16 * i + 4 * qd + p;
                V[((size_t)r * 128 + row) * 2048 + col] = acc[i][j][p];
            }
        }
}

// ---------------- k3 fallback: fp32 VALU ----------------
__global__ __launch_bounds__(256) void k3_votes(const float* __restrict__ Mb,
                                                const float* __restrict__ CW,
                                                float* __restrict__ V) {
    __shared__ float As[16][132];
    __shared__ float Bs[16][132];
    const int tid = threadIdx.x;
    const int r = blockIdx.z;
    const int n0 = blockIdx.x * 128;
    const float* A = Mb + (size_t)r * 128 * 1024;
    const float* Bm = CW + (size_t)r * 1024 * 2048;
    float* C = V + (size_t)r * 128 * 2048;
    const int ty = tid >> 4, tx = tid & 15;
    const int k4 = (tid & 3) * 4, row = tid >> 2;
    const int n4 = (tid & 31) * 4, krow = tid >> 5;

    float acc[8][8];
#pragma unroll
    for (int i = 0; i < 8; i++)
#pragma unroll
        for (int j = 0; j < 8; j++) acc[i][j] = 0.f;

    for (int k0 = 0; k0 < 1024; k0 += 16) {
#pragma unroll
        for (int rr = 0; rr < 2; rr++) {
            const int m = row + rr * 64;
            float4 av = *(const float4*)(A + (size_t)m * 1024 + k0 + k4);
            As[k4 + 0][m] = av.x; As[k4 + 1][m] = av.y;
            As[k4 + 2][m] = av.z; As[k4 + 3][m] = av.w;
            const int k = krow + rr * 8;
            float4 bv = *(const float4*)(Bm + (size_t)(k0 + k) * 2048 + n0 + n4);
            *(float4*)(&Bs[k][n4]) = bv;
        }
        __syncthreads();
#pragma unroll
        for (int k = 0; k < 16; k++) {
            float a[8], b[8];
            *(float4*)(a)     = *(const float4*)(&As[k][ty * 8]);
            *(float4*)(a + 4) = *(const float4*)(&As[k][ty * 8 + 4]);
            *(float4*)(b)     = *(const float4*)(&Bs[k][tx * 8]);
            *(float4*)(b + 4) = *(const float4*)(&Bs[k][tx * 8 + 4]);
#pragma unroll
            for (int i = 0; i < 8; i++)
#pragma unroll
                for (int j = 0; j < 8; j++) acc[i][j] += a[i] * b[j];
        }
        __syncthreads();
    }
#pragma unroll
    for (int i = 0; i < 8; i++) {
        const int m = ty * 8 + i;
#pragma unroll
        for (int j = 0; j < 8; j += 4) {
            float4 v;
            v.x = acc[i][j + 0]; v.y = acc[i][j + 1];
            v.z = acc[i][j + 2]; v.w = acc[i][j + 3];
            *(float4*)(C + (size_t)m * 2048 + n0 + tx * 8 + j) = v;
        }
    }
}

// ---------------- k4: dynamic routing ----------------
__global__ __launch_bounds__(256) void k4_routing(const float* __restrict__ V,
                                                  float* __restrict__ out) {
    __shared__ float logits[8 * 128];
    __shared__ float route[8 * 128];
    __shared__ float preact[128 * 16];
    __shared__ float act[128 * 16];
    __shared__ float fred[128];
    const int b = blockIdx.x, tid = threadIdx.x;
    const float* vb = V + (size_t)b * 2048;

    for (int i = tid; i < 1024; i += 256) logits[i] = 0.f;
    __syncthreads();

    for (int it = 0; it < 3; it++) {
        {
            const int r = tid >> 5, g = tid & 31;
            float l[4];
#pragma unroll
            for (int q = 0; q < 4; q++) l[q] = logits[r * 128 + g + q * 32];
            float mx = fmaxf(fmaxf(l[0], l[1]), fmaxf(l[2], l[3]));
            for (int msk = 16; msk; msk >>= 1) mx = fmaxf(mx, __shfl_xor(mx, msk, 32));
            float e[4], s = 0.f;
#pragma unroll
            for (int q = 0; q < 4; q++) { e[q] = expf(l[q] - mx); s += e[q]; }
            for (int msk = 16; msk; msk >>= 1) s += __shfl_xor(s, msk, 32);
            float inv = 1.f / s;
#pragma unroll
            for (int q = 0; q < 4; q++) route[r * 128 + g + q * 32] = e[q] * inv;
        }
        __syncthreads();
        for (int i = tid; i < 2048; i += 256) {
            const int c = i >> 4;
            float a = 0.f;
#pragma unroll
            for (int r = 0; r < 8; r++)
                a += route[r * 128 + c] * vb[(size_t)r * 128 * 2048 + i];
            preact[i] = a;
        }
        __syncthreads();
        if (tid < 128) {
            float n2 = 0.f;
#pragma unroll
            for (int o = 0; o < 16; o++) { float p = preact[tid * 16 + o]; n2 += p * p; }
            fred[tid] = sqrtf(n2) / (1.f + n2);
        }
        __syncthreads();
        for (int i = tid; i < 2048; i += 256) act[i] = preact[i] * fred[i >> 4];
        __syncthreads();
        for (int i = tid; i < 1024; i += 256) {
            const int r = i >> 7, c = i & 127;
            float d = 0.f;
#pragma unroll
            for (int o = 0; o < 16; o++)
                d += vb[(size_t)r * 128 * 2048 + c * 16 + o] * act[c * 16 + o];
            logits[i] += d;
        }
        __syncthreads();
    }
    if (tid < 128) {
        float n2 = 0.f;
#pragma unroll
        for (int o = 0; o < 16; o++) { float a = act[tid * 16 + o]; n2 += a * a; }
        out[(size_t)b * 128 + tid] = sqrtf(n2);
    }
}

extern "C" void kernel_launch(void* const* d_in, const int* in_sizes, int n_in,
                              void* d_out, int out_size, void* d_ws, size_t ws_size,
                              hipStream_t stream) {
    const float* x   = (const float*)d_in[0];
    const float* WS1 = (const float*)d_in[1];
    const float* WS2 = (const float*)d_in[2];
    const float* cw  = (const float*)d_in[3];
    float* out = (float*)d_out;

    char* ws = (char*)d_ws;
    float* m_buf = (float*)ws;                                        // 4 MiB
    float* votes = (float*)(ws + ((size_t)4 << 20));                  // 8 MiB
    unsigned short* W1h = (unsigned short*)(ws + ((size_t)12 << 20)); // 8 MiB
    unsigned short* W2h = (unsigned short*)(ws + ((size_t)20 << 20)); // 8 MiB

    const bool use_cw  = ws_size >= ((size_t)124 << 20);
    const bool use_xbf = ws_size >= ((size_t)190 << 20);
    unsigned short* CWh = (unsigned short*)(ws + ((size_t)28 << 20)); // 32 MiB
    unsigned short* CWl = (unsigned short*)(ws + ((size_t)60 << 20)); // 32 MiB
    unsigned short* Xbf = (unsigned short*)(ws + ((size_t)92 << 20)); // 64 MiB
    const size_t hh_off = use_xbf ? ((size_t)156 << 20)
                        : use_cw  ? ((size_t)92 << 20)
                                  : ((size_t)28 << 20);
    unsigned short* Hh = (unsigned short*)(ws + hh_off);

    // chunk size: Hh holds 8r x CB x 256 x 512 bf16 = CB * 2 MiB
    int CB = 16;
    {
        const size_t perb = (size_t)2 << 20;
        size_t avail = (ws_size > hh_off) ? (ws_size - hh_off) : perb;
        int cbmax = (int)(avail / perb);
        if (cbmax < 1) cbmax = 1;
        if (CB > cbmax) CB = cbmax;
    }

    const int nW4 = (8 * 512 * 1024) / 4;
    k0_hi<<<dim3((nW4 + 255) / 256), dim3(256), 0, stream>>>(WS1, W1h, nW4);
    k0_hi<<<dim3((nW4 + 255) / 256), dim3(256), 0, stream>>>(WS2, W2h, nW4);
    if (use_cw)
        k0_tsplit<<<dim3(32, 16, 8), dim3(256), 0, stream>>>(cw, CWh, CWl);
    if (use_xbf) {
        const int nX4 = (128 * 256 * 1024) / 4;
        k0_hi<<<dim3((nX4 + 255) / 256), dim3(256), 0, stream>>>(x, Xbf, nX4);
    }

    for (int b0 = 0; b0 < 128; b0 += CB) {
        const int bc = (128 - b0 < CB) ? (128 - b0) : CB;
        if (use_xbf)
            k1_direct<<<dim3(bc * 2, 4, 8), dim3(256), 0, stream>>>(
                Xbf + (size_t)b0 * 256 * 1024, W1h, Hh, bc);
        else
            k1_lds<<<dim3(bc * 2, 4, 8), dim3(256), 0, stream>>>(
                x + (size_t)b0 * 256 * 1024, W1h, Hh, bc);
        k2_mfma<<<dim3(bc, 16, 8), dim3(256), 0, stream>>>(
            Hh, W2h, x, m_buf, b0, bc);
    }
    if (use_cw)
        k3_votes_mfma<<<dim3(8, 32), dim3(256), 0, stream>>>(m_buf, CWh, CWl, votes);
    else
        k3_votes<<<dim3(16, 1, 8), dim3(256), 0, stream>>>(m_buf, cw, votes);
    k4_routing<<<dim3(128), dim3(256), 0, stream>>>(votes, out);
}